// Round 1
// 2802.058 us; speedup vs baseline: 1.4607x; 1.4607x over previous
//
#include <hip/hip_runtime.h>
#include <math.h>

#define HW_ 65536
#define NCHUNK 16
typedef long long i64;
#define TWO_PI 6.283185307179586476925f

typedef __bf16 bf16x8 __attribute__((ext_vector_type(8)));
typedef float f32x4 __attribute__((ext_vector_type(4)));

#define MFMA16(A,B,C) __builtin_amdgcn_mfma_f32_16x16x32_bf16(A,B,C,0,0,0)

__device__ __forceinline__ float sigm(float x){ return 1.0f/(1.0f+expf(-x)); }

// convert 8 consecutive fp32 to a bf16x8 A-fragment
__device__ __forceinline__ bf16x8 cvt_w8(const float* wp){
  float4 w0 = *(const float4*)wp;
  float4 w1 = *(const float4*)(wp+4);
  bf16x8 r;
  r[0]=(__bf16)w0.x; r[1]=(__bf16)w0.y; r[2]=(__bf16)w0.z; r[3]=(__bf16)w0.w;
  r[4]=(__bf16)w1.x; r[5]=(__bf16)w1.y; r[6]=(__bf16)w1.z; r[7]=(__bf16)w1.w;
  return r;
}

// ---------------- resize (nb,3,128,128) -> (nb,3,256,256) bilinear half-pixel ----------------
__global__ __launch_bounds__(256) void k_resize(const float* __restrict__ x, float* __restrict__ R, int b0){
  int idx = blockIdx.x*256 + threadIdx.x;
  int ox = idx & 255;
  int oy = (idx >> 8) & 255;
  int bc = idx >> 16;                               // lb*3 + c
  int lb = bc/3; int c = bc - lb*3;
  float sx = ox*0.5f - 0.25f;
  float sy = oy*0.5f - 0.25f;
  int x0 = (int)floorf(sx); float fx = sx - (float)x0;
  int y0 = (int)floorf(sy); float fy = sy - (float)y0;
  int x1 = min(x0+1,127); int y1 = min(y0+1,127);
  x0 = max(x0,0); y0 = max(y0,0);
  const float* p = x + ((i64)(b0+lb)*3 + c)*16384;
  float v00=p[y0*128+x0], v01=p[y0*128+x1], v10=p[y1*128+x0], v11=p[y1*128+x1];
  R[idx] = (1.0f-fy)*((1.0f-fx)*v00 + fx*v01) + fy*((1.0f-fx)*v10 + fx*v11);
}

// ---------------- conv3x3 3->64: block per (b,row), all 64 outs per thread ----------------
__global__ __launch_bounds__(256) void k_conv3(const float* __restrict__ R, const float* __restrict__ w, float* __restrict__ out){
  int y = blockIdx.x & 255; int b = blockIdx.x >> 8; int t = threadIdx.x;
  float win[27];
  #pragma unroll
  for (int ci=0;ci<3;ci++){
    #pragma unroll
    for (int ky=0;ky<3;ky++){
      int yy = y+ky-1;
      const float* ip = R + (((i64)(b*3+ci))<<16) + yy*256;
      #pragma unroll
      for (int kx=0;kx<3;kx++){
        int xx = t+kx-1;
        float v = 0.f;
        if ((unsigned)yy<256u && (unsigned)xx<256u) v = ip[xx];
        win[ci*9+ky*3+kx] = v;
      }
    }
  }
  i64 obase = ((i64)b<<22) + (y<<8) + t;
  for (int o=0;o<64;o++){
    const float* wp = w + o*27;
    float acc=0.f;
    #pragma unroll
    for (int j=0;j<27;j++) acc += wp[j]*win[j];
    out[obase + ((i64)o<<16)] = acc;
  }
}

// ---------------- DFT coeffs (7 reals incl. DC) + pooled mean per (b,c) ----------------
__global__ __launch_bounds__(256) void k_dft(const float* __restrict__ xc, float* __restrict__ coeff, float* __restrict__ pooled){
  __shared__ float tc[256], ts[256];
  __shared__ float red[256];
  int t = threadIdx.x;
  float ang = TWO_PI * ((float)t/256.0f);
  tc[t] = cosf(ang); ts[t] = sinf(ang);
  __syncthreads();
  int bc = blockIdx.x;
  const float* p = xc + (i64)bc*HW_;
  float s=0, cr=0, ci=0, rr=0, ri=0, dr=0, di=0;
  for (int i=t; i<HW_; i+=256){
    float v = p[i];
    int col = i & 255, row = i >> 8, ds = (row+col)&255;
    s  += v;
    cr += v*tc[col]; ci += v*ts[col];
    rr += v*tc[row]; ri += v*ts[row];
    dr += v*tc[ds];  di += v*ts[ds];
  }
  float vals[7] = {s,cr,ci,rr,ri,dr,di};
  for (int j=0;j<7;j++){
    red[t] = vals[j]; __syncthreads();
    for (int st=128; st>0; st>>=1){ if (t<st) red[t]+=red[t+st]; __syncthreads(); }
    if (t==0) vals[j] = red[0];
    __syncthreads();
  }
  if (t==0){
    const float sc = 1.0f/65536.0f;
    for (int j=0;j<7;j++) coeff[bc*8+j] = vals[j]*sc;
    pooled[bc] = vals[0]*sc;
  }
}

// ---------------- threshold MLP -> per-batch mask flag ----------------
__global__ __launch_bounds__(64) void k_thr(const float* __restrict__ pooled, const float* __restrict__ w1,
                      const float* __restrict__ w2, float* __restrict__ flag){
  __shared__ float hid[8];
  int b = blockIdx.x; int t = threadIdx.x;
  if (t < 8){
    float a = 0.f;
    for (int c=0;c<64;c++) a += pooled[b*64+c]*w1[t*64+c];
    hid[t] = 0.5f*a*(1.0f+erff(a*0.70710678118654752440f));
  }
  __syncthreads();
  if (t==0){
    float t0=0,t1=0;
    for (int k=0;k<8;k++){ t0 += hid[k]*w2[k]; t1 += hid[k]*w2[8+k]; }
    int h_ = (int)(2.0f*sigm(t0));
    int w_ = (int)(2.0f*sigm(t1));
    flag[b] = (h_>0 && w_>0) ? 1.0f : 0.0f;
  }
}

// ---------------- fused: high/low reconstruction + conv1x1 (q path of cca0/cca1) ----------------
template<int WHICH>   // 0 = high, 1 = low
__global__ __launch_bounds__(256) void k_convq_fre(const float* __restrict__ xc, const float* __restrict__ coeff,
      const float* __restrict__ flag, const float* __restrict__ qw, float* __restrict__ out){
  __shared__ float tc[256], ts[256];
  int t = threadIdx.x;
  float ang = TWO_PI * ((float)t/256.0f);
  tc[t]=cosf(ang); ts[t]=sinf(ang);
  __syncthreads();
  int blk2 = blockIdx.x & 127; int b = blockIdx.x >> 7;
  int px0 = blk2*512 + 2*t;
  int x0 = px0 & 255; int y = px0 >> 8;
  float fl = flag[b];
  float crow = tc[y], srow = ts[y];
  int d0 = (x0 + y) & 255;
  int d1 = (x0 + 1 + y) & 255;
  float c0=tc[x0], s0=ts[x0], c1=tc[x0+1], s1=ts[x0+1];
  float cd0=tc[d0], sd0=ts[d0], cd1=tc[d1], sd1=ts[d1];
  i64 ibase = ((i64)b<<22) + px0;
  float2 xv[64];
  #pragma unroll
  for (int c=0;c<64;c++){
    const float* cf = coeff + ((b<<6)+c)*8;
    float F00=cf[0], cR=cf[1], cI=cf[2], rR=cf[3], rI=cf[4], dR=cf[5], dI=cf[6];
    float2 xr = *(const float2*)(xc + ibase + ((i64)c<<16));
    float re0 = F00 + cR*c0 + cI*s0 + rR*crow + rI*srow + dR*cd0 + dI*sd0;
    float im0 =       cI*c0 - cR*s0 + rI*crow - rR*srow + dI*cd0 - dR*sd0;
    float re1 = F00 + cR*c1 + cI*s1 + rR*crow + rI*srow + dR*cd1 + dI*sd1;
    float im1 =       cI*c1 - cR*s1 + rI*crow - rR*srow + dI*cd1 - dR*sd1;
    re0*=fl; im0*=fl; re1*=fl; im1*=fl;
    float v0, v1;
    if (WHICH==1){ v0 = sqrtf(re0*re0+im0*im0); v1 = sqrtf(re1*re1+im1*im1); }
    else { float h0=xr.x-re0, h1=xr.y-re1; v0 = sqrtf(h0*h0+im0*im0); v1 = sqrtf(h1*h1+im1*im1); }
    xv[c] = make_float2(v0,v1);
  }
  for (int o=0;o<64;o++){
    const float* wr = qw + o*64;
    float ax=0.f, ay=0.f;
    #pragma unroll
    for (int c=0;c<64;c++){ float wv=wr[c]; ax += xv[c].x*wv; ay += xv[c].y*wv; }
    *(float2*)(out + ibase + ((i64)o<<16)) = make_float2(ax,ay);
  }
}

// =====================================================================================
// MFMA pixel-matmul family: per wave, one 64px x 64out strip.
// A-frag (weights, row-major [O][64] fp32): lane holds row = m*16+(lane&15),
//   k = s*32 + (lane>>4)*8 + j  (8 consecutive fp32 -> bf16x8).
// B-frag (input planes [c][px]): col = lane&15 -> px = p0 + 4*(lane&15) + e (e=0..3 via
//   float4 components -> 4 parity fragments), k = s*32 + (lane>>4)*8 + j (per-plane loads).
// C/D: col(px)=lane&15, row(out)=(lane>>4)*4+reg  [verified m89 layout].
// =====================================================================================

// loads B for one strip: bq[s][j] float4 (4 px per lane); builds bf[s][e] frags
#define MM_LOAD_B(in_ptr) \
  float4 bq[2][8]; \
  _Pragma("unroll") \
  for (int s=0;s<2;s++){ \
    const float* bp = (in_ptr) + ((i64)(s*32 + kg*8)<<16) + 4*lm; \
    _Pragma("unroll") \
    for (int j=0;j<8;j++) bq[s][j] = *(const float4*)(bp + ((i64)j<<16)); \
  } \
  bf16x8 bf[2][4]; \
  _Pragma("unroll") \
  for (int s=0;s<2;s++){ \
    bf16x8 f0,f1,f2,f3; \
    _Pragma("unroll") \
    for (int j=0;j<8;j++){ \
      f0[j]=(__bf16)bq[s][j].x; f1[j]=(__bf16)bq[s][j].y; \
      f2[j]=(__bf16)bq[s][j].z; f3[j]=(__bf16)bq[s][j].w; \
    } \
    bf[s][0]=f0; bf[s][1]=f1; bf[s][2]=f2; bf[s][3]=f3; \
  }

#define MM_COMPUTE(Wbase) \
  bf16x8 af[4][2]; \
  _Pragma("unroll") \
  for (int m=0;m<4;m++){ \
    _Pragma("unroll") \
    for (int s=0;s<2;s++) af[m][s] = cvt_w8((Wbase) + (m*16 + lm)*64 + s*32 + kg*8); \
  } \
  f32x4 acc[4][4]; \
  _Pragma("unroll") \
  for (int m=0;m<4;m++){ \
    _Pragma("unroll") \
    for (int e=0;e<4;e++){ f32x4 z = {0.f,0.f,0.f,0.f}; acc[m][e]=z; } \
  } \
  _Pragma("unroll") \
  for (int m=0;m<4;m++){ \
    _Pragma("unroll") \
    for (int e=0;e<4;e++){ \
      _Pragma("unroll") \
      for (int s=0;s<2;s++) acc[m][e] = MFMA16(af[m][s], bf[s][e], acc[m][e]); \
    } \
  }

// ---------------- conv1x1 64->128 (k and v pre-tensors), MFMA ----------------
__global__ __launch_bounds__(256) void k_mm_kv(const float* __restrict__ in, const float* __restrict__ w,
      float* __restrict__ kout, float* __restrict__ vout){
  int t = threadIdx.x;
  int lane = t & 63, wvi = t >> 6;
  i64 px0 = (i64)blockIdx.x*256 + wvi*64;
  int b = (int)(px0 >> 16);
  int p0 = (int)(px0 & (HW_-1));
  i64 ibase = ((i64)b<<22) + p0;
  int lm = lane & 15, kg = lane >> 4;
  MM_LOAD_B(in + ibase)
  #pragma unroll
  for (int half=0; half<2; half++){
    float* outp = half ? vout : kout;
    const float* Wb = w + half*4096;
    MM_COMPUTE(Wb)
    #pragma unroll
    for (int m=0;m<4;m++){
      #pragma unroll
      for (int r=0;r<4;r++){
        int oc = m*16 + kg*4 + r;
        float4 st = make_float4(acc[m][0][r], acc[m][1][r], acc[m][2][r], acc[m][3][r]);
        *(float4*)(outp + ibase + ((i64)oc<<16) + 4*lm) = st;
      }
    }
  }
}

// ---------------- plain conv1x1 64->64, MFMA ----------------
__global__ __launch_bounds__(256) void k_mm_64(const float* __restrict__ in, const float* __restrict__ w,
      float* __restrict__ out){
  int t = threadIdx.x;
  int lane = t & 63, wvi = t >> 6;
  i64 px0 = (i64)blockIdx.x*256 + wvi*64;
  int b = (int)(px0 >> 16);
  int p0 = (int)(px0 & (HW_-1));
  i64 ibase = ((i64)b<<22) + p0;
  int lm = lane & 15, kg = lane >> 4;
  MM_LOAD_B(in + ibase)
  MM_COMPUTE(w)
  #pragma unroll
  for (int m=0;m<4;m++){
    #pragma unroll
    for (int r=0;r<4;r++){
      int oc = m*16 + kg*4 + r;
      float4 st = make_float4(acc[m][0][r], acc[m][1][r], acc[m][2][r], acc[m][3][r]);
      *(float4*)(out + ibase + ((i64)oc<<16) + 4*lm) = st;
    }
  }
}

// ---------------- final mconv: M x v, *para1 + y*para2, MFMA ----------------
__global__ __launch_bounds__(256) void k_mm_fin(const float* __restrict__ v, const float* __restrict__ M,
      const float* __restrict__ para1, const float* __restrict__ para2,
      const float* __restrict__ yin, float* __restrict__ out){
  int t = threadIdx.x;
  int lane = t & 63, wvi = t >> 6;
  i64 px0 = (i64)blockIdx.x*256 + wvi*64;
  int b = (int)(px0 >> 16);
  int p0 = (int)(px0 & (HW_-1));
  i64 ibase = ((i64)b<<22) + p0;
  int lm = lane & 15, kg = lane >> 4;
  MM_LOAD_B(v + ibase)
  const float* Wb = M + ((i64)b<<12);
  MM_COMPUTE(Wb)
  #pragma unroll
  for (int m=0;m<4;m++){
    #pragma unroll
    for (int r=0;r<4;r++){
      int oc = m*16 + kg*4 + r;
      float p1 = para1[oc], p2 = para2[oc];
      float4 yv = *(const float4*)(yin + ibase + ((i64)oc<<16) + 4*lm);
      float4 st = make_float4(acc[m][0][r]*p1 + yv.x*p2,
                              acc[m][1][r]*p1 + yv.y*p2,
                              acc[m][2][r]*p1 + yv.z*p2,
                              acc[m][3][r]*p1 + yv.w*p2);
      *(float4*)(out + ibase + ((i64)oc<<16) + 4*lm) = st;
    }
  }
}

// ---------------- fused dw3x3(q)+dw3x3(k)+stats: per (b,head,chunk16rows) ----------------
__global__ __launch_bounds__(256) void k_statsdw(const float* __restrict__ qpre, const float* __restrict__ kpre,
        const float* __restrict__ qdw, const float* __restrict__ kdw, float* __restrict__ part){
  __shared__ float wql[72], wkl[72];
  __shared__ float red[4][80];
  int blk = blockIdx.x;
  int chunk = blk & (NCHUNK-1);
  int bh = blk / NCHUNK;
  int h = bh & 7, b = bh >> 3;
  int x = threadIdx.x;
  if (x < 72){ wql[x] = qdw[h*72 + x]; wkl[x] = kdw[h*72 + x]; }
  __syncthreads();
  const float* qp = qpre + (((i64)((b<<6) + (h<<3)))<<16);
  const float* kp = kpre + (((i64)((b<<6) + (h<<3)))<<16);
  float dot[8][8], qn[8], kn[8];
  #pragma unroll
  for (int a=0;a<8;a++){ qn[a]=0.f; kn[a]=0.f;
    #pragma unroll
    for (int d=0;d<8;d++) dot[a][d]=0.f; }
  int y0 = chunk*16;
  for (int rr=0; rr<16; rr++){
    int y = y0+rr;
    float qv[8], kv[8];
    #pragma unroll
    for (int a=0;a<8;a++){
      float aq=0.f, ak=0.f;
      #pragma unroll
      for (int ky=0;ky<3;ky++){
        int yy=y+ky-1; bool yok = ((unsigned)yy<256u);
        const float* qrow = qp + ((i64)a<<16) + yy*256;
        const float* krow = kp + ((i64)a<<16) + yy*256;
        #pragma unroll
        for (int kx=0;kx<3;kx++){
          int xx=x+kx-1; bool ok = yok && ((unsigned)xx<256u);
          float qv_ = ok ? qrow[xx] : 0.f;
          float kv_ = ok ? krow[xx] : 0.f;
          aq += wql[a*9+ky*3+kx]*qv_;
          ak += wkl[a*9+ky*3+kx]*kv_;
        }
      }
      qv[a]=aq; kv[a]=ak;
    }
    #pragma unroll
    for (int a=0;a<8;a++){
      qn[a]+=qv[a]*qv[a]; kn[a]+=kv[a]*kv[a];
      #pragma unroll
      for (int d=0;d<8;d++) dot[a][d]+=qv[a]*kv[d];
    }
  }
  int lane = x & 63, wv = x >> 6;
  #pragma unroll
  for (int j=0;j<80;j++){
    float v;
    if (j<64) v = dot[j>>3][j&7];
    else if (j<72) v = qn[j-64];
    else v = kn[j-72];
    #pragma unroll
    for (int off=32; off; off>>=1) v += __shfl_down(v, off);
    if (lane==0) red[wv][j] = v;
  }
  __syncthreads();
  for (int j=x; j<80; j+=256)
    part[(i64)blk*80 + j] = red[0][j]+red[1][j]+red[2][j]+red[3][j];
}

__global__ __launch_bounds__(128) void k_stats_fin(const float* __restrict__ part, float* __restrict__ stats){
  int bh = blockIdx.x; int t = threadIdx.x;
  if (t < 80){
    float s=0.f;
    for (int c=0;c<NCHUNK;c++) s += part[((i64)bh*NCHUNK+c)*80 + t];
    stats[bh*80+t] = s;
  }
}

// ---------------- softmax + fold attn into per-batch 64x64 M ----------------
__global__ __launch_bounds__(64) void k_attn_m(const float* __restrict__ stats, const float* __restrict__ temp,
                         const float* __restrict__ projw, float* __restrict__ M){
  __shared__ float attn[8][8][8];
  int b = blockIdx.x; int t = threadIdx.x;
  int h = t >> 3, cc = t & 7;
  const float* st = stats + (b*8+h)*80;
  float nq = fmaxf(sqrtf(st[64+cc]), 1e-12f);
  float tmp = temp[h];
  float s[8];
  float mx = -1e30f;
  #pragma unroll
  for (int d=0;d<8;d++){
    float nk = fmaxf(sqrtf(st[72+d]), 1e-12f);
    s[d] = st[cc*8+d]/(nq*nk)*tmp;
    mx = fmaxf(mx, s[d]);
  }
  float sum=0.f;
  #pragma unroll
  for (int d=0;d<8;d++){ s[d]=expf(s[d]-mx); sum+=s[d]; }
  float inv = 1.0f/sum;
  #pragma unroll
  for (int d=0;d<8;d++) attn[h][cc][d] = s[d]*inv;
  __syncthreads();
  int o = t;
  for (int hh=0; hh<8; hh++){
    #pragma unroll
    for (int d=0; d<8; d++){
      float acc=0.f;
      #pragma unroll
      for (int c2=0;c2<8;c2++) acc += projw[o*64 + hh*8 + c2]*attn[hh][c2][d];
      M[((i64)b*64 + o)*64 + hh*8 + d] = acc;
    }
  }
}

// ---------------- depthwise 3x3 (v path): row-swept, 16 rows/thread-column ----------------
__global__ __launch_bounds__(256) void k_dw(const float* __restrict__ in, const float* __restrict__ wd,
                                            float* __restrict__ out){
  int blk = blockIdx.x;              // ((b*64+c)*16 + yt)
  int yt = blk & 15; int c = (blk>>4)&63; int b = blk>>10;
  int x = threadIdx.x;
  const float* ip = in + (((i64)((b<<6)+c))<<16);
  float* op = out + (((i64)((b<<6)+c))<<16);
  const float* wp = wd + c*9;
  int y0 = yt*16;
  float a0,a1,a2, b0,b1,b2;
  {
    int yy = y0-1;
    if ((unsigned)yy<256u){ const float* rp = ip + yy*256;
      a0 = (x>0)? rp[x-1]:0.f; a1 = rp[x]; a2 = (x<255)? rp[x+1]:0.f;
    } else { a0=a1=a2=0.f; }
    const float* rp = ip + y0*256;
    b0 = (x>0)? rp[x-1]:0.f; b1 = rp[x]; b2 = (x<255)? rp[x+1]:0.f;
  }
  for (int rr=0;rr<16;rr++){
    float d0,d1,d2;
    int yy = y0+rr+1;
    if ((unsigned)yy<256u){ const float* rp = ip + yy*256;
      d0 = (x>0)? rp[x-1]:0.f; d1 = rp[x]; d2 = (x<255)? rp[x+1]:0.f;
    } else { d0=d1=d2=0.f; }
    float acc = wp[0]*a0+wp[1]*a1+wp[2]*a2 + wp[3]*b0+wp[4]*b1+wp[5]*b2 + wp[6]*d0+wp[7]*d1+wp[8]*d2;
    op[(y0+rr)*256 + x] = acc;
    a0=b0;a1=b1;a2=b2; b0=d0;b1=d1;b2=d2;
  }
}

// ---------------- mconv variants: per-batch 64x64 over v, 2 px/thread ----------------
__global__ __launch_bounds__(256) void k_mconv_hi(const float* __restrict__ v, const float* __restrict__ M,
        float* __restrict__ out, float* __restrict__ mx, float* __restrict__ mn){
  int blk2 = blockIdx.x & 127; int b = blockIdx.x >> 7; int t = threadIdx.x;
  int px0 = blk2*512 + 2*t;
  i64 ibase = ((i64)b<<22) + px0;
  float2 xv[64];
  #pragma unroll
  for (int c=0;c<64;c++) xv[c] = *(const float2*)(v + ibase + ((i64)c<<16));
  const float* Mp = M + (b<<12);
  float mX=-1e30f, mY=-1e30f, sX=0.f, sY=0.f;
  for (int o=0;o<64;o++){
    const float* wr = Mp + o*64;
    float ax=0.f, ay=0.f;
    #pragma unroll
    for (int c=0;c<64;c++){ float wv=wr[c]; ax += xv[c].x*wv; ay += xv[c].y*wv; }
    *(float2*)(out + ibase + ((i64)o<<16)) = make_float2(ax,ay);
    mX=fmaxf(mX,ax); mY=fmaxf(mY,ay); sX+=ax; sY+=ay;
  }
  i64 pbase = ((i64)b<<16) + px0;
  *(float2*)(mx+pbase) = make_float2(mX,mY);
  *(float2*)(mn+pbase) = make_float2(sX*(1.0f/64.0f), sY*(1.0f/64.0f));
}

__global__ __launch_bounds__(256) void k_mconv_lo(const float* __restrict__ v, const float* __restrict__ M,
        float* __restrict__ out, float* __restrict__ spart){
  __shared__ float ls[4][64], lm[4][64];
  int blk2 = blockIdx.x & 127; int b = blockIdx.x >> 7; int t = threadIdx.x;
  int px0 = blk2*512 + 2*t;
  i64 ibase = ((i64)b<<22) + px0;
  float2 xv[64];
  #pragma unroll
  for (int c=0;c<64;c++) xv[c] = *(const float2*)(v + ibase + ((i64)c<<16));
  const float* Mp = M + (b<<12);
  int lane = t & 63, wv = t >> 6;
  for (int o=0;o<64;o++){
    const float* wr = Mp + o*64;
    float ax=0.f, ay=0.f;
    #pragma unroll
    for (int c=0;c<64;c++){ float wvv=wr[c]; ax += xv[c].x*wvv; ay += xv[c].y*wvv; }
    *(float2*)(out + ibase + ((i64)o<<16)) = make_float2(ax,ay);
    float s = ax+ay, m = fmaxf(ax,ay);
    #pragma unroll
    for (int off=32; off; off>>=1){ s += __shfl_xor(s,off); m = fmaxf(m, __shfl_xor(m,off)); }
    if (lane==0){ ls[wv][o]=s; lm[wv][o]=m; }
  }
  __syncthreads();
  if (t<64){
    float s = ls[0][t]+ls[1][t]+ls[2][t]+ls[3][t];
    float m = fmaxf(fmaxf(lm[0][t],lm[1][t]), fmaxf(lm[2][t],lm[3][t]));
    spart[(i64)blockIdx.x*128 + t*2]   = s;
    spart[(i64)blockIdx.x*128 + t*2+1] = m;
  }
}

// ---------------- refine small kernels ----------------
__global__ __launch_bounds__(64) void k_spatfin(const float* __restrict__ spart, float* __restrict__ lmean, float* __restrict__ lmax){
  int b = blockIdx.x; int c = threadIdx.x;
  float s=0.f, m=-1e30f;
  for (int r=0;r<128;r++){
    s += spart[(i64)(b*128+r)*128 + c*2];
    m = fmaxf(m, spart[(i64)(b*128+r)*128 + c*2+1]);
  }
  lmean[b*64+c] = s*(1.0f/65536.0f);
  lmax[b*64+c]  = m;
}

__global__ __launch_bounds__(64) void k_cw(const float* __restrict__ mean, const float* __restrict__ mxv,
                     const float* __restrict__ w1, const float* __restrict__ w2, float* __restrict__ cw){
  __shared__ float ha[4], hm[4];
  int b = blockIdx.x; int t = threadIdx.x;
  if (t < 4){
    float sa=0.f, sm_=0.f;
    for (int c=0;c<64;c++){ sa += w1[t*64+c]*mean[b*64+c]; sm_ += w1[t*64+c]*mxv[b*64+c]; }
    ha[t] = fmaxf(sa, 0.f); hm[t] = fmaxf(sm_, 0.f);
  }
  __syncthreads();
  float a=0.f;
  #pragma unroll
  for (int j=0;j<4;j++) a += w2[t*4+j]*(ha[j]+hm[j]);
  cw[b*64+t] = sigm(a);
}

__global__ __launch_bounds__(256) void k_sw(const float* __restrict__ mx, const float* __restrict__ mn,
                     const float* __restrict__ w, float* __restrict__ sw){
  int row = blockIdx.x & 255; int b = blockIdx.x >> 8; int t = threadIdx.x;
  const float* m0 = mx + ((i64)b<<16);
  const float* m1 = mn + ((i64)b<<16);
  float acc=0.f;
  for (int ky=0;ky<7;ky++){
    int yy = row+ky-3; if ((unsigned)yy>255u) continue;
    for (int kx=0;kx<7;kx++){
      int xx = t+kx-3; if ((unsigned)xx>255u) continue;
      acc += w[ky*7+kx]*m0[yy*256+xx] + w[49+ky*7+kx]*m1[yy*256+xx];
    }
  }
  sw[((i64)b<<16) + row*256 + t] = sigm(acc);
}

// ---------------- fused comb + refine conv1x1 ----------------
__global__ __launch_bounds__(256) void k_comb_rproj(const float* __restrict__ lo2, const float* __restrict__ hi2,
        const float* __restrict__ swb, const float* __restrict__ cwb,
        const float* __restrict__ w, const float* __restrict__ bias, float* __restrict__ out){
  int blk2 = blockIdx.x & 127; int b = blockIdx.x >> 7; int t = threadIdx.x;
  int px0 = blk2*512 + 2*t;
  i64 ibase = ((i64)b<<22) + px0;
  float2 sw2 = *(const float2*)(swb + ((i64)b<<16) + px0);
  float2 xv[64];
  #pragma unroll
  for (int c=0;c<64;c++){
    float2 l = *(const float2*)(lo2 + ibase + ((i64)c<<16));
    float2 h = *(const float2*)(hi2 + ibase + ((i64)c<<16));
    float cwv = cwb[(b<<6)+c];
    xv[c] = make_float2(l.x*sw2.x + h.x*cwv, l.y*sw2.y + h.y*cwv);
  }
  for (int o=0;o<64;o++){
    const float* wr = w + o*64;
    float ax=0.f, ay=0.f;
    #pragma unroll
    for (int c=0;c<64;c++){ float wv=wr[c]; ax += xv[c].x*wv; ay += xv[c].y*wv; }
    ax += bias[o]; ay += bias[o];
    *(float2*)(out + ibase + ((i64)o<<16)) = make_float2(ax,ay);
  }
}

// =====================================================================================
extern "C" void kernel_launch(void* const* d_in, const int* in_sizes, int n_in,
                              void* d_out, int out_size, void* d_ws, size_t ws_size,
                              hipStream_t stream){
  const float* x      = (const float*)d_in[0];
  const float* y      = (const float*)d_in[1];
  const float* conv1w = (const float*)d_in[2];
  const float* ratew1 = (const float*)d_in[3];
  const float* ratew2 = (const float*)d_in[4];
  const float* temp   = (const float*)d_in[5];
  const float* qw     = (const float*)d_in[6];
  const float* qdw    = (const float*)d_in[7];
  const float* kvw    = (const float*)d_in[8];
  const float* kvdw   = (const float*)d_in[9];
  const float* projw  = (const float*)d_in[10];
  const float* spw    = (const float*)d_in[11];
  const float* cgw1   = (const float*)d_in[12];
  const float* cgw2   = (const float*)d_in[13];
  const float* rprojw = (const float*)d_in[14];
  const float* rprojb = (const float*)d_in[15];
  const float* para1  = (const float*)d_in[16];
  const float* para2  = (const float*)d_in[17];
  float* D = (float*)d_out;

  // pick largest batch-group size whose footprint fits: 3 big units + pool
  int nb = 8;
  for (;;){
    size_t unit = (size_t)nb*64*HW_;
    size_t pool = (size_t)nb*3*HW_            // Rbuf
                + (size_t)nb*512 + (size_t)nb*64 + 64
                + (size_t)nb*8*NCHUNK*80      // part
                + (size_t)nb*8*80             // stats
                + (size_t)nb*64*64            // M
                + 3*(size_t)nb*HW_            // mxmap, mnmap, swb
                + (size_t)nb*128*128          // spart
                + 3*(size_t)nb*64;            // lmean, lmax, cwb
    if ((3*unit + pool)*sizeof(float) <= ws_size || nb==1) break;
    nb >>= 1;
  }

  size_t unit = (size_t)nb*64*HW_;
  float* U0 = (float*)d_ws;
  float* U1 = U0 + unit;
  float* U2 = U1 + unit;
  float* sm = U2 + unit;
  float* Rbuf  = sm;  sm += (size_t)nb*3*HW_;
  float* coeff = sm;  sm += (size_t)nb*512;
  float* pooled= sm;  sm += (size_t)nb*64;
  float* flagb = sm;  sm += 64;
  float* part  = sm;  sm += (size_t)nb*8*NCHUNK*80;
  float* stats = sm;  sm += (size_t)nb*8*80;
  float* Mb    = sm;  sm += (size_t)nb*64*64;
  float* mxmap = sm;  sm += (size_t)nb*HW_;
  float* mnmap = sm;  sm += (size_t)nb*HW_;
  float* swb   = sm;  sm += (size_t)nb*HW_;
  float* spart = sm;  sm += (size_t)nb*128*128;
  float* lmean = sm;  sm += (size_t)nb*64;
  float* lmax  = sm;  sm += (size_t)nb*64;
  float* cwb   = sm;  sm += (size_t)nb*64;

  for (int b0 = 0; b0 < 8; b0 += nb){
    const float* yg = y + (i64)b0*64*HW_;
    float*       Dg = D + (i64)b0*64*HW_;

    // frontend
    k_resize <<<nb*3*256, 256,0,stream>>>(x, Rbuf, b0);
    k_conv3  <<<nb*256,   256,0,stream>>>(Rbuf, conv1w, U0);           // xc = U0
    k_dft    <<<nb*64,    256,0,stream>>>(U0, coeff, pooled);
    k_thr    <<<nb,       64, 0,stream>>>(pooled, ratew1, ratew2, flagb);

    // cca0 (a = high, from xc)
    k_convq_fre<0><<<nb*128,256,0,stream>>>(U0, coeff, flagb, qw + 0*4096, U1);   // qpre=U1
    k_mm_kv  <<<nb*256,256,0,stream>>>(yg, kvw + 0*8192, U2, Dg);                 // kpre=U2, vpre=Dg
    k_statsdw <<<nb*8*NCHUNK,256,0,stream>>>(U1, U2, qdw + 0*576, kvdw + 0*1152, part);
    k_stats_fin<<<nb*8,  128,0,stream>>>(part, stats);
    k_dw      <<<nb*1024,256,0,stream>>>(Dg, kvdw + 0*1152 + 576, U1);            // v=U1
    k_attn_m  <<<nb,     64, 0,stream>>>(stats, temp + 0*8, projw + 0*4096, Mb);
    k_mconv_hi<<<nb*128, 256,0,stream>>>(U1, Mb, U2, mxmap, mnmap);               // high2=U2

    // cca1 (a = low, from xc)  [xc dead after this conv]
    k_convq_fre<1><<<nb*128,256,0,stream>>>(U0, coeff, flagb, qw + 1*4096, U1);   // qpre=U1
    k_mm_kv  <<<nb*256,256,0,stream>>>(yg, kvw + 1*8192, U0, Dg);                 // kpre=U0, vpre=Dg
    k_statsdw <<<nb*8*NCHUNK,256,0,stream>>>(U1, U0, qdw + 1*576, kvdw + 1*1152, part);
    k_stats_fin<<<nb*8,  128,0,stream>>>(part, stats);
    k_dw      <<<nb*1024,256,0,stream>>>(Dg, kvdw + 1*1152 + 576, U1);            // v=U1
    k_attn_m  <<<nb,     64, 0,stream>>>(stats, temp + 1*8, projw + 1*4096, Mb);
    k_mconv_lo<<<nb*128, 256,0,stream>>>(U1, Mb, Dg, spart);                      // low2=Dg

    // refine: high2=U2, low2=Dg -> agg=U0
    k_spatfin <<<nb,     64, 0,stream>>>(spart, lmean, lmax);
    k_cw      <<<nb,     64, 0,stream>>>(lmean, lmax, cgw1, cgw2, cwb);
    k_sw      <<<nb*256, 256,0,stream>>>(mxmap, mnmap, spw, swb);
    k_comb_rproj<<<nb*128,256,0,stream>>>(Dg, U2, swb, cwb, rprojw, rprojb, U0);  // agg=U0

    // cca2 (q from y, kv from agg=U0)
    k_mm_64  <<<nb*256,256,0,stream>>>(yg, qw + 2*4096, U1);                      // qpre=U1
    k_mm_kv  <<<nb*256,256,0,stream>>>(U0, kvw + 2*8192, U2, Dg);                 // kpre=U2, vpre=Dg
    k_statsdw <<<nb*8*NCHUNK,256,0,stream>>>(U1, U2, qdw + 2*576, kvdw + 2*1152, part);
    k_stats_fin<<<nb*8,  128,0,stream>>>(part, stats);
    k_dw      <<<nb*1024,256,0,stream>>>(Dg, kvdw + 2*1152 + 576, U1);            // v=U1
    k_attn_m  <<<nb,     64, 0,stream>>>(stats, temp + 2*8, projw + 2*4096, Mb);
    k_mm_fin <<<nb*256,256,0,stream>>>(U1, Mb, para1, para2, yg, Dg);             // out
  }
}